// Round 1
// baseline (381.042 us; speedup 1.0000x reference)
//
#include <hip/hip_runtime.h>
#include <hip/hip_bf16.h>

typedef unsigned short ushort_t;
typedef unsigned int uint_t;

typedef __bf16 bf16x8 __attribute__((ext_vector_type(8)));
typedef float f32x4 __attribute__((ext_vector_type(4)));

__device__ __forceinline__ float bf2f(ushort_t u) {
    return __uint_as_float(((uint_t)u) << 16);
}
__device__ __forceinline__ ushort_t f2bf(float f) {
    uint_t x = __float_as_uint(f);
    uint_t r = (x + 0x7FFFu + ((x >> 16) & 1u)) >> 16;
    return (ushort_t)r;
}
__device__ __forceinline__ float sigmoidf_fast(float x) {
    return 1.0f / (1.0f + __expf(-x));
}

// ---------------------------------------------------------------------------
// Kernel 1: permute+transpose W2 (fp32 256x768) -> W2t (bf16 768x256).
// New column index n' = kk*256 + dir*128 + d  <-  old col = dir*384 + d*3 + kk.
// Stored row-major [n'][k] (i.e. B^T) so GEMM B-fragments are contiguous in K.
// ---------------------------------------------------------------------------
__global__ __launch_bounds__(256) void permute_w2(const float* __restrict__ W2,
                                                  ushort_t* __restrict__ W2t) {
    int i = blockIdx.x * 256 + threadIdx.x;   // 768*256 total
    int np = i >> 8;        // n' in [0,768)
    int k  = i & 255;       // k  in [0,256)
    int kk  = np >> 8;      // 0..2
    int rem = np & 255;
    int dir = rem >> 7;
    int d   = rem & 127;
    int oc = dir * 384 + d * 3 + kk;
    W2t[np * 256 + k] = f2bf(W2[k * 768 + oc]);
}

// ---------------------------------------------------------------------------
// Kernel 2: fused patch-extract + GEMM1 (K=12, register weights) + SRU scan
// over Wp. Block = (hp,b) sequence (896 blocks), thread = channel (dir,d).
// Writes H1[( (hp*112+wp)*8 + b )*256 + ch] as bf16.
// ---------------------------------------------------------------------------
__global__ __launch_bounds__(256) void scan1(const float* __restrict__ x,
                                             const float* __restrict__ W1,
                                             const float* __restrict__ wc1,
                                             const float* __restrict__ b1,
                                             ushort_t* __restrict__ H1) {
    __shared__ float patch[112 * 12];   // 5.4 KB, 16B-aligned rows of 12 floats
    const int n1 = blockIdx.x;
    const int hp = n1 >> 3, b = n1 & 7;
    const int tid = threadIdx.x;

    // Stage the 112 patches of this (hp,b) row: 6 image rows x 224 px.
    for (int e = tid; e < 1344; e += 256) {
        int c = e / 448;
        int rem = e % 448;
        int wh = rem / 224;
        int pos = rem % 224;            // 2*wp + ww
        float v = x[((b * 3 + c) * 224 + (2 * hp + wh)) * 224 + pos];
        patch[(pos >> 1) * 12 + c * 4 + wh * 2 + (pos & 1)] = v;
    }

    // Per-thread weights: W1 columns tid*4 .. tid*4+3 (u0,u1,u2,u3), 12 rows.
    float4 w[12];
    const float4* W1v = (const float4*)W1;
#pragma unroll
    for (int j = 0; j < 12; ++j) w[j] = W1v[j * 256 + tid];

    const float vf = wc1[tid],       vr = wc1[256 + tid];
    const float bfv = b1[tid],       brv = b1[256 + tid];
    const int dir = tid >> 7;

    __syncthreads();

    float cst = 0.0f;
    for (int t = 0; t < 112; ++t) {
        const int tt = dir ? (111 - t) : t;
        const float4* pp = (const float4*)(patch + tt * 12);
        float4 p0 = pp[0], p1 = pp[1], p2 = pp[2];
        float pj[12] = {p0.x, p0.y, p0.z, p0.w, p1.x, p1.y, p1.z, p1.w,
                        p2.x, p2.y, p2.z, p2.w};
        float u0 = 0.f, u1 = 0.f, u2 = 0.f, u3 = 0.f;
#pragma unroll
        for (int j = 0; j < 12; ++j) {
            float pv = pj[j];
            u0 = fmaf(w[j].x, pv, u0);
            u1 = fmaf(w[j].y, pv, u1);
            u2 = fmaf(w[j].z, pv, u2);
            u3 = fmaf(w[j].w, pv, u3);
        }
        float f = sigmoidf_fast(u1 + vf * cst + bfv);
        cst = f * cst + (1.0f - f) * u0;
        float r = sigmoidf_fast(u2 + vr * cst + brv);
        float h = r * cst + (1.0f - r) * u3;
        H1[((size_t)(hp * 112 + tt) * 8 + b) * 256 + tid] = f2bf(h);
    }
}

// ---------------------------------------------------------------------------
// Kernel 3: bf16 MFMA GEMM: U2(M x 768) = H1(M x 256) @ W2t^T.
// 128x128 tile, BK=32, 4 waves each computing 64x64 (4x4 of 16x16x32 frags),
// global_load_lds width=16 staging. M=100352, N=768, K=256 divide exactly.
// ---------------------------------------------------------------------------
__global__ __launch_bounds__(256) void gemm2(const ushort_t* __restrict__ A,
                                             const ushort_t* __restrict__ Bt,
                                             ushort_t* __restrict__ Cc) {
    __shared__ ushort_t As[128 * 32];   // [row][k] 64B rows
    __shared__ ushort_t Bs[128 * 32];   // [n][k]   64B rows
    const int m0 = blockIdx.y * 128;
    const int n0 = blockIdx.x * 128;
    const int tid = threadIdx.x;
    const int w = tid >> 6, lane = tid & 63;
    const int wm = w >> 1, wn = w & 1;
    const int lr = lane >> 2;           // 0..15 (row within 16-row chunk)
    const int lc = (lane & 3) * 8;      // element offset (8 bf16 = 16B)
    const int ln16 = lane & 15;
    const int k8 = (lane >> 4) * 8;

    f32x4 acc[4][4] = {};

    for (int kb = 0; kb < 256; kb += 32) {
        if (kb) __syncthreads();        // prior reads done before overwrite
#pragma unroll
        for (int q = 0; q < 2; ++q) {
            int r = w * 32 + q * 16;    // wave-uniform base row of this 1KB chunk
            const ushort_t* gA = A + (size_t)(m0 + r + lr) * 256 + kb + lc;
            __builtin_amdgcn_global_load_lds(
                (const __attribute__((address_space(1))) uint_t*)gA,
                (__attribute__((address_space(3))) uint_t*)(As + r * 32), 16, 0, 0);
            const ushort_t* gB = Bt + (size_t)(n0 + r + lr) * 256 + kb + lc;
            __builtin_amdgcn_global_load_lds(
                (const __attribute__((address_space(1))) uint_t*)gB,
                (__attribute__((address_space(3))) uint_t*)(Bs + r * 32), 16, 0, 0);
        }
        __syncthreads();                // drains vmcnt: staging visible

        bf16x8 af[4], bf[4];
#pragma unroll
        for (int i = 0; i < 4; ++i) {
            int ra = wm * 64 + i * 16 + ln16;
            af[i] = *(const bf16x8*)(As + ra * 32 + k8);
            int rb = wn * 64 + i * 16 + ln16;
            bf[i] = *(const bf16x8*)(Bs + rb * 32 + k8);
        }
#pragma unroll
        for (int i = 0; i < 4; ++i)
#pragma unroll
            for (int j = 0; j < 4; ++j)
                acc[i][j] = __builtin_amdgcn_mfma_f32_16x16x32_bf16(
                    af[i], bf[j], acc[i][j], 0, 0, 0);
    }

    // Epilogue: C/D layout col=lane&15, row=(lane>>4)*4+reg.
    const int rq = (lane >> 4) * 4;
#pragma unroll
    for (int i = 0; i < 4; ++i)
#pragma unroll
        for (int j = 0; j < 4; ++j)
#pragma unroll
            for (int r = 0; r < 4; ++r) {
                int gm = m0 + wm * 64 + i * 16 + rq + r;
                int gn = n0 + wn * 64 + j * 16 + ln16;
                Cc[(size_t)gm * 768 + gn] = f2bf(acc[i][j][r]);
            }
}

// ---------------------------------------------------------------------------
// Kernel 4: SRU scan over Hp. Block = (wp,b) sequence, thread = channel.
// u_k at U2[m*768 + k*256 + ch]; xprime = sqrt(2)*H1[m*256+ch]. Output fp32.
// ---------------------------------------------------------------------------
__global__ __launch_bounds__(256) void scan2(const ushort_t* __restrict__ U2,
                                             const ushort_t* __restrict__ H1,
                                             const float* __restrict__ wc2,
                                             const float* __restrict__ b2,
                                             float* __restrict__ H2) {
    const int n2 = blockIdx.x;
    const int wp = n2 >> 3, b = n2 & 7;
    const int tid = threadIdx.x;
    const int dir = tid >> 7;
    const float vf = wc2[tid],  vr = wc2[256 + tid];
    const float bfv = b2[tid],  brv = b2[256 + tid];
    const float SCALE_X = 1.41421356237309515f;

    float cst = 0.0f;
    for (int t = 0; t < 112; ++t) {
        const int tt = dir ? (111 - t) : t;
        const size_t m = (size_t)(tt * 112 + wp) * 8 + b;
        const ushort_t* u = U2 + m * 768;
        float u0 = bf2f(u[tid]);
        float u1 = bf2f(u[256 + tid]);
        float u2 = bf2f(u[512 + tid]);
        float xp = bf2f(H1[m * 256 + tid]) * SCALE_X;
        float f = sigmoidf_fast(u1 + vf * cst + bfv);
        cst = f * cst + (1.0f - f) * u0;
        float r = sigmoidf_fast(u2 + vr * cst + brv);
        H2[m * 256 + tid] = r * cst + (1.0f - r) * xp;
    }
}

// ---------------------------------------------------------------------------
// Kernel 5: transpose H2 (hp,wp,b,ch) -> out (b,ch,hp,wp). LDS 112x64 tile,
// stride 65 (+1 pad): both phases coalesced, LDS conflict-free.
// ---------------------------------------------------------------------------
__global__ __launch_bounds__(256) void transpose_out(const float* __restrict__ H2,
                                                     float* __restrict__ out) {
    __shared__ float tile[112 * 65];    // 29 KB
    const int bid = blockIdx.x;         // 8 * 112 * 4
    const int cchunk = bid & 3;
    const int hp = (bid >> 2) % 112;
    const int b = bid / (4 * 112);
    const int tid = threadIdx.x;
    const int ch0 = cchunk * 64;

    for (int i = tid; i < 112 * 64; i += 256) {
        int wp = i >> 6;
        int c = i & 63;
        tile[wp * 65 + c] = H2[((size_t)(hp * 112 + wp) * 8 + b) * 256 + ch0 + c];
    }
    __syncthreads();
    for (int i = tid; i < 64 * 112; i += 256) {
        int c = i / 112;
        int wp = i % 112;
        out[((size_t)(b * 256 + ch0 + c) * 112 + hp) * 112 + wp] = tile[wp * 65 + c];
    }
}

// ---------------------------------------------------------------------------
// Launch. Workspace layout (bytes):
//   H1  bf16 100352*256  @ 0          (51,380,224)
//   U2  bf16 100352*768  @ 51380224   (154,140,672)
//   W2t bf16 768*256     @ 205520896  (393,216)
//   H2  fp32 100352*256  @ 205914112  (102,760,448)   total 308,674,560 B
// ---------------------------------------------------------------------------
extern "C" void kernel_launch(void* const* d_in, const int* in_sizes, int n_in,
                              void* d_out, int out_size, void* d_ws, size_t ws_size,
                              hipStream_t stream) {
    const float* x   = (const float*)d_in[0];
    const float* W1  = (const float*)d_in[1];
    const float* wc1 = (const float*)d_in[2];
    const float* b1  = (const float*)d_in[3];
    const float* W2  = (const float*)d_in[4];
    const float* wc2 = (const float*)d_in[5];
    const float* b2  = (const float*)d_in[6];
    float* out = (float*)d_out;

    char* ws = (char*)d_ws;
    ushort_t* H1  = (ushort_t*)(ws);
    ushort_t* U2  = (ushort_t*)(ws + 51380224);
    ushort_t* W2t = (ushort_t*)(ws + 51380224 + 154140672);
    float*    H2  = (float*)(ws + 51380224 + 154140672 + 393216);

    permute_w2<<<768, 256, 0, stream>>>(W2, W2t);
    scan1<<<896, 256, 0, stream>>>(x, W1, wc1, b1, H1);
    gemm2<<<dim3(6, 784), 256, 0, stream>>>(H1, W2t, U2);
    scan2<<<896, 256, 0, stream>>>(U2, H1, wc2, b2, H2);
    transpose_out<<<8 * 112 * 4, 256, 0, stream>>>(H2, out);
}